// Round 10
// baseline (495.346 us; speedup 1.0000x reference)
//
#include <hip/hip_runtime.h>
#include <hip/hip_bf16.h>
#include <math.h>

// WindowAttention on MI355X — round 13: QKV GEMM fused into attention.
// Round-12 chunking regressed (small grids underutilize 256 CUs) — reverted.
// Profile showed a fixed 60µs harness memset per iteration; remaining lever
// is traffic. The (b,h) attn partition tiles the QKV GEMM exactly (no FLOP
// duplication), so each attn block computes its own Y-slice:
//   stage x[b] (49x256, fp32->bf16, GEMM-proven XOR swizzle) -> LDS;
//   wave0: Q (2 n-tiles), wave1: K, waves2/3: V halves — W-fragments read
//   directly from L2-resident qwb (384 KB); write sQ/sK/sVt in the exact
//   layouts the proven attn phases consume; continue unchanged.
// Deletes cast_x + gemm_qkv (−113 µs kernels, −400 MB traffic). Garbage
// policy: x rows >=49 staged clamped to row 48 (finite) => pad cols killed
// exactly by wmp=-1e30; no LDS zeroing needed. sP aliases sX (dead after
// QKV). Pipeline: pre_masks -> fused_attn -> gemm_proj (3 dispatches).

#define B_TOT   2048
#define NTOK    49
#define CDIM    256
#define NHEAD   8
#define HDIM    32
#define MROWS   (B_TOT * NTOK)   // 100352
#define QKV_N   (3 * CDIM)       // 768

#define LOG2E 1.4426950408889634f

#if __has_builtin(__builtin_amdgcn_exp2f)
#define EXP2(x) __builtin_amdgcn_exp2f(x)
#else
#define EXP2(x) __expf((x) * 0.6931471805599453f)
#endif

typedef __attribute__((ext_vector_type(8))) short short8;   // 8 bf16 (4 VGPRs)
typedef __attribute__((ext_vector_type(4))) float floatx4;  // MFMA acc

typedef unsigned int u32_g __attribute__((address_space(1)));
typedef unsigned int u32_l __attribute__((address_space(3)));

__device__ __forceinline__ void gld_lds16(const void* g, void* l) {
    __builtin_amdgcn_global_load_lds((const u32_g*)g, (u32_l*)l, 16, 0, 0);
}

__device__ __forceinline__ void cast8(const float* __restrict__ in,
                                      __hip_bfloat16* __restrict__ out, int i) {
    const float4* p = (const float4*)in + (size_t)i * 2;
    float4 a = p[0], b = p[1];
    __hip_bfloat16 r[8];
    r[0] = __float2bfloat16(a.x); r[1] = __float2bfloat16(a.y);
    r[2] = __float2bfloat16(a.z); r[3] = __float2bfloat16(a.w);
    r[4] = __float2bfloat16(b.x); r[5] = __float2bfloat16(b.y);
    r[6] = __float2bfloat16(b.z); r[7] = __float2bfloat16(b.w);
    *(uint4*)(out + (size_t)i * 8) = *(const uint4*)r;
}

__device__ __forceinline__ void exp4(const float* __restrict__ in,
                                     float* __restrict__ out, int i) {
    float4 a = ((const float4*)in)[i];
    float4 r;
    r.x = EXP2(a.x * LOG2E); r.y = EXP2(a.y * LOG2E);
    r.z = EXP2(a.z * LOG2E); r.w = EXP2(a.w * LOG2E);
    ((float4*)out)[i] = r;
}

// ---------------------------------------------------------------------------
// once-per-launch prep: weights cast + mask tables. Block-range dispatch:
//  [    0,   96): cast qkv_w  (24,576 8-chunks)
//  [   96,  128): cast proj_w (8,192 8-chunks)
//  [  128, 8320): wmp[win][h][r64][c64] = (wmask + relpos)*log2e, pad -1e30
//  [ 8320,13122): Fgp = exp(fg), float4
//  [13122,17924): Bgp = exp(bg), float4
// ---------------------------------------------------------------------------
__global__ __launch_bounds__(256) void pre_masks(
    const float* __restrict__ qkv_w,   // (768, 256)
    const float* __restrict__ proj_w,  // (256, 256)
    const float* __restrict__ wmask,   // (64, 49, 49)
    const float* __restrict__ table,   // (169, 8)
    const float* __restrict__ fg,      // (2048, 49, 49)
    const float* __restrict__ bg,      // (2048, 49, 49)
    __hip_bfloat16* __restrict__ qwb,
    __hip_bfloat16* __restrict__ pwb,
    float* __restrict__ wmp,           // (64, 8, 64, 64)
    float* __restrict__ Fgp,
    float* __restrict__ Bgp)
{
    const int bid = blockIdx.x;
    const int t = threadIdx.x;
    if (bid < 96) {
        cast8(qkv_w, qwb, bid * 256 + t);
    } else if (bid < 128) {
        cast8(proj_w, pwb, (bid - 96) * 256 + t);
    } else if (bid < 8320) {
        const int idx = (bid - 128) * 256 + t;   // < 2^21
        const int col = idx & 63, row = (idx >> 6) & 63;
        const int h = (idx >> 12) & 7, win = idx >> 15;
        float v = -1e30f;
        if (row < 49 && col < 49) {
            const int qi = row / 7, qj = row % 7;
            const int ki = col / 7, kj = col % 7;
            const int ti = (qi - ki + 6) * 13 + (qj - kj + 6);
            v = (wmask[win * 2401 + row * 49 + col] + table[ti * 8 + h]) * LOG2E;
        }
        wmp[idx] = v;
    } else if (bid < 13122) {
        exp4(fg, Fgp, (bid - 8320) * 256 + t);
    } else {
        exp4(bg, Bgp, (bid - 13122) * 256 + t);
    }
}

// ---------------------------------------------------------------------------
// MFMA GEMM (proj): out(M,256) = Obf(M,256) @ pw(256,256)^T + bias.
// Proven round-9 structure: gld_lds staging, 128x128 tile, 4 K-steps.
// General bijective XCD swizzle.
// ---------------------------------------------------------------------------
template<int NDIM, bool OUT_BF16>
__global__ __launch_bounds__(256) void gemm_mfma(
    const __hip_bfloat16* __restrict__ A,
    const __hip_bfloat16* __restrict__ W,
    const float* __restrict__ bias,
    void* __restrict__ Yv)
{
    const int K = 256;
    __shared__ short As[128 * 64];
    __shared__ short Bs[128 * 64];
    const int t = threadIdx.x;
    const int lane = t & 63, w = t >> 6;
    const int wr = w >> 1, wc = w & 1;
    const int q = lane >> 4, l15 = lane & 15;

    constexpr int NBX = NDIM / 128;          // grid x
    const int nwg = NBX * (int)gridDim.y;
    const int orig = (int)blockIdx.y * NBX + (int)blockIdx.x;
    const int xcd = orig & 7, rest = orig >> 3;
    const int qq = nwg >> 3, rr = nwg & 7;
    const int bid = (xcd < rr ? xcd * (qq + 1) : rr * (qq + 1) + (xcd - rr) * qq) + rest;
    const int m0 = (bid / NBX) * 128, n0 = (bid % NBX) * 128;

    const int srow = t >> 3, skb = t & 7;
    const int gkb = skb ^ (srow & 7);
    const __hip_bfloat16* Ag = A + (size_t)(m0 + srow) * K + gkb * 8;
    const __hip_bfloat16* Wg = W + (size_t)(n0 + srow) * K + gkb * 8;

    floatx4 acc[4][4] = {};
    const int swz = l15 & 7;

    for (int k0 = 0; k0 < K; k0 += 64) {
        __syncthreads();
        #pragma unroll
        for (int i = 0; i < 4; i++) {
            gld_lds16(Ag + (size_t)(i * 32) * K + k0, &As[i * 2048 + w * 512]);
            gld_lds16(Wg + (size_t)(i * 32) * K + k0, &Bs[i * 2048 + w * 512]);
        }
        __syncthreads();
        #pragma unroll
        for (int kk = 0; kk < 2; kk++) {
            const int kbs = ((kk << 2) + q) ^ swz;
            short8 af[4], bf[4];
            #pragma unroll
            for (int i = 0; i < 4; i++) {
                af[i] = *(const short8*)&As[(wr * 64 + i * 16 + l15) * 64 + kbs * 8];
                bf[i] = *(const short8*)&Bs[(wc * 64 + i * 16 + l15) * 64 + kbs * 8];
            }
            #pragma unroll
            for (int i = 0; i < 4; i++)
                #pragma unroll
                for (int j = 0; j < 4; j++)
                    acc[i][j] = __builtin_amdgcn_mfma_f32_16x16x32_bf16(
                        af[i], bf[j], acc[i][j], 0, 0, 0);
        }
    }

    #pragma unroll
    for (int j = 0; j < 4; j++) {
        const int n = n0 + wc * 64 + j * 16 + l15;
        const float bv = bias[n];
        #pragma unroll
        for (int i = 0; i < 4; i++) {
            #pragma unroll
            for (int r = 0; r < 4; r++) {
                const int m = m0 + wr * 64 + i * 16 + q * 4 + r;
                const float val = acc[i][j][r] + bv;
                if (OUT_BF16)
                    ((__hip_bfloat16*)Yv)[(size_t)m * NDIM + n] = __float2bfloat16(val);
                else
                    ((float*)Yv)[(size_t)m * NDIM + n] = val;
            }
        }
    }
}

// ---------------------------------------------------------------------------
// Fused QKV + attention. One block (4 waves) per (b,h).
// LDS 47.6 KB: sX 64x256 bf16 (XOR-swizzled 8-chunks; aliased as sP after
// QKV) | sQ 64x40 | sK 64x40 | sVt 32x72.
// Phase 0: stage x (fp32->bf16, rows>=49 clamped to 48); QKV via MFMA with
//   W-fragments from global (L2-resident qwb): wave0 Q, wave1 K, wave2 V[d<16],
//   wave3 V[d>=16]; +bias; write sQ/sK row-major (stride 40), sVt transposed.
// Phases B/C: byte-identical math to rounds 8-12 (passed, absmax 0.00195).
// Garbage: pad rows finite (clamped) => pad cols: acc finite + wmp=-1e30 =>
//   e0=0 exact; pad q-rows -> s0=0 -> rcp=inf -> pc NaN -> discarded at store.
// Block swizzle: 8 heads of one b on one XCD => x/fg/bg L2-local.
// ---------------------------------------------------------------------------
__global__ __launch_bounds__(256, 3) void fused_attn(
    const float* __restrict__ x,            // (B*49, 256) fp32
    const __hip_bfloat16* __restrict__ Wq,  // qwb (768, 256) bf16
    const float* __restrict__ qkv_b,        // (768)
    const float* __restrict__ wmp,          // (64, 8, 64, 64)
    const float* __restrict__ Fgp,          // (B, 49, 49) = exp(fg)
    const float* __restrict__ Bgp,          // (B, 49, 49) = exp(bg)
    __hip_bfloat16* __restrict__ O)         // (B*49, 256) bf16 -> ws
{
    __shared__ __hip_bfloat16 sX[64 * 256];   // 32 KB; reused as sP later
    __shared__ __hip_bfloat16 sQ[64 * 40];
    __shared__ __hip_bfloat16 sK[64 * 40];
    __shared__ __hip_bfloat16 sVt[32 * 72];
    __hip_bfloat16* sP = sX;                  // sX dead after QKV phase

    const int blk = blockIdx.x;
    const int b = (blk >> 6) * 8 + (blk & 7);
    const int h = (blk >> 3) & 7;
    const int t = threadIdx.x;
    const int w = t >> 6, lane = t & 63;
    const int quad = lane >> 4, l15 = lane & 15;
    const float SC = 0.17677669529663687f * LOG2E;  // hd^-0.5 * log2e

    // ---- mask prefetch (imm-offset loads; latency overlaps staging) ----
    const float* wmb = wmp + (((size_t)(b & 63) * 8 + h) << 12);
    const float* fgb = Fgp + (size_t)b * (NTOK * NTOK);
    const float* bgb = Bgp + (size_t)b * (NTOK * NTOK);
    float mwm[16], mfg[16], mbg[16];
    #pragma unroll
    for (int r = 0; r < 4; r++) {
        const int row = w * 16 + quad * 4 + r;
        const int rc49 = min(row, 48) * 49;
        const float* pw = wmb + row * 64 + l15;
        const float* pf = fgb + rc49 + l15;
        const float* pb = bgb + rc49 + l15;
        mwm[r * 4 + 0] = pw[0];  mwm[r * 4 + 1] = pw[16];
        mwm[r * 4 + 2] = pw[32]; mwm[r * 4 + 3] = pw[48];
        mfg[r * 4 + 0] = pf[0];  mfg[r * 4 + 1] = pf[16];
        mfg[r * 4 + 2] = pf[32]; mfg[r * 4 + 3] = fgb[rc49 + 48];
        mbg[r * 4 + 0] = pb[0];  mbg[r * 4 + 1] = pb[16];
        mbg[r * 4 + 2] = pb[32]; mbg[r * 4 + 3] = bgb[rc49 + 48];
    }

    // ---- phase 0a: stage x fp32->bf16, XOR-swizzled 8-elem chunks ----
    // i-th float4 (4 floats): row=i>>6 (clamped src), c=i&63. chunk kb=c>>1,
    // half=c&1; dest elem = row*256 + ((kb^(row&7))<<3) + half*4 (8B store).
    // One row per wave-instr: 64 lanes read 1KB contiguous (coalesced).
    const float* xb_ = x + (size_t)b * NTOK * CDIM;
    #pragma unroll
    for (int it = 0; it < 16; it++) {
        const int i = t + it * 256;
        const int row = i >> 6, c = i & 63;
        const float4 v4 = *(const float4*)(xb_ + (size_t)min(row, 48) * CDIM + c * 4);
        __hip_bfloat16 hv[4];
        hv[0] = __float2bfloat16(v4.x); hv[1] = __float2bfloat16(v4.y);
        hv[2] = __float2bfloat16(v4.z); hv[3] = __float2bfloat16(v4.w);
        *(uint2*)&sX[row * 256 + (((c >> 1) ^ (row & 7)) << 3) + (c & 1) * 4] =
            *(const uint2*)hv;
    }
    __syncthreads();

    // ---- phase 0b: QKV = x @ Wq[head-slice]^T + bias, via MFMA ----
    // wave0: Q n-tiles {0,1}; wave1: K {0,1}; wave2: V {0}; wave3: V {1}.
    const int ntw = (w < 2) ? 2 : 1;
    const int wbase = (w == 0) ? h * HDIM
                    : (w == 1) ? CDIM + h * HDIM
                               : 2 * CDIM + h * HDIM + ((w == 3) ? 16 : 0);
    floatx4 qa[4][2] = {};
    #pragma unroll
    for (int s = 0; s < 8; s++) {            // K-chunks of 32
        short8 axf[4];
        #pragma unroll
        for (int i = 0; i < 4; i++)
            axf[i] = *(const short8*)&sX[(i * 16 + l15) * 256 +
                                         ((((s << 2) | quad) ^ (l15 & 7)) << 3)];
        #pragma unroll
        for (int jt = 0; jt < 2; jt++) {
            if (jt < ntw) {
                short8 wf = *(const short8*)&Wq[(size_t)(wbase + jt * 16 + l15) * CDIM
                                                + s * 32 + quad * 8];
                #pragma unroll
                for (int i = 0; i < 4; i++)
                    qa[i][jt] = __builtin_amdgcn_mfma_f32_16x16x32_bf16(
                        axf[i], wf, qa[i][jt], 0, 0, 0);
            }
        }
    }
    // write QKV to LDS (C-layout: col=l15 -> n/d, row=quad*4+r -> token m)
    #pragma unroll
    for (int jt = 0; jt < 2; jt++) {
        if (jt < ntw) {
            const float bv = qkv_b[wbase + jt * 16 + l15];
            #pragma unroll
            for (int i = 0; i < 4; i++) {
                #pragma unroll
                for (int r = 0; r < 4; r++) {
                    const int m = i * 16 + quad * 4 + r;
                    const __hip_bfloat16 hv = __float2bfloat16(qa[i][jt][r] + bv);
                    if (w == 0)      sQ[m * 40 + jt * 16 + l15] = hv;
                    else if (w == 1) sK[m * 40 + jt * 16 + l15] = hv;
                    else             sVt[((w == 2) ? l15 : 16 + l15) * 72 + m] = hv;
                }
            }
        }
    }
    __syncthreads();

    // ---- phase B: S = Q K^T in registers ----
    floatx4 acc[4];
    {
        short8 af = *(const short8*)(sQ + (w * 16 + l15) * 40 + quad * 8);
        #pragma unroll
        for (int nt = 0; nt < 4; nt++) {
            short8 bf = *(const short8*)(sK + (nt * 16 + l15) * 40 + quad * 8);
            floatx4 z = {};
            acc[nt] = __builtin_amdgcn_mfma_f32_16x16x32_bf16(af, bf, z, 0, 0, 0);
        }
    }

    // unnormalized exponentials (exp2 domain; wmp pre-scaled by log2e).
    float e0[16];
    #pragma unroll
    for (int r = 0; r < 4; r++)
        #pragma unroll
        for (int nt = 0; nt < 4; nt++)
            e0[r * 4 + nt] = EXP2(fmaf(acc[nt][r], SC, mwm[r * 4 + nt]));
    #pragma unroll
    for (int i = 0; i < 16; i++) mfg[i] *= e0[i];   // ef
    #pragma unroll
    for (int i = 0; i < 16; i++) mbg[i] *= e0[i];   // eb

    // 3 row-sum reductions, quad-local 4-step shuffles.
    float s0[4], sf[4], sb[4];
    #pragma unroll
    for (int r = 0; r < 4; r++) {
        s0[r] = (e0[r * 4] + e0[r * 4 + 1]) + (e0[r * 4 + 2] + e0[r * 4 + 3]);
        sf[r] = (mfg[r * 4] + mfg[r * 4 + 1]) + (mfg[r * 4 + 2] + mfg[r * 4 + 3]);
        sb[r] = (mbg[r * 4] + mbg[r * 4 + 1]) + (mbg[r * 4 + 2] + mbg[r * 4 + 3]);
    }
    #pragma unroll
    for (int st = 1; st < 16; st <<= 1)
        #pragma unroll
        for (int r = 0; r < 4; r++) {
            s0[r] += __shfl_xor(s0[r], st);
            sf[r] += __shfl_xor(sf[r], st);
            sb[r] += __shfl_xor(sb[r], st);
        }

    float pc[16];
    #pragma unroll
    for (int r = 0; r < 4; r++) {
        const float r0 = __builtin_amdgcn_rcpf(s0[r]);
        const float rf = __builtin_amdgcn_rcpf(sf[r]);
        const float rb = -__builtin_amdgcn_rcpf(sb[r]);
        #pragma unroll
        for (int nt = 0; nt < 4; nt++) {
            const int i = r * 4 + nt;
            pc[i] = fmaf(mbg[i], rb, fmaf(mfg[i], rf, e0[i] * r0));
        }
    }

    // P -> LDS (bf16, row-major stride 72; sP aliases sX — all sX reads done
    // before the barrier above).
    #pragma unroll
    for (int r = 0; r < 4; r++) {
        const int row = w * 16 + quad * 4 + r;
        #pragma unroll
        for (int nt = 0; nt < 4; nt++)
            sP[row * 72 + nt * 16 + l15] = __float2bfloat16(pc[r * 4 + nt]);
    }
    __syncthreads();

    // ---- phase C: O = P @ V ----
    floatx4 o0 = {}, o1 = {};
    {
        short8 a0  = *(const short8*)(sP + (w * 16 + l15) * 72 + quad * 8);
        short8 a1  = *(const short8*)(sP + (w * 16 + l15) * 72 + 32 + quad * 8);
        short8 b00 = *(const short8*)(sVt + l15 * 72 + quad * 8);
        short8 b01 = *(const short8*)(sVt + l15 * 72 + 32 + quad * 8);
        short8 b10 = *(const short8*)(sVt + (16 + l15) * 72 + quad * 8);
        short8 b11 = *(const short8*)(sVt + (16 + l15) * 72 + 32 + quad * 8);
        o0 = __builtin_amdgcn_mfma_f32_16x16x32_bf16(a0, b00, o0, 0, 0, 0);
        o0 = __builtin_amdgcn_mfma_f32_16x16x32_bf16(a1, b01, o0, 0, 0, 0);
        o1 = __builtin_amdgcn_mfma_f32_16x16x32_bf16(a0, b10, o1, 0, 0, 0);
        o1 = __builtin_amdgcn_mfma_f32_16x16x32_bf16(a1, b11, o1, 0, 0, 0);
    }
    __hip_bfloat16* Ob = O + (size_t)b * NTOK * CDIM + h * HDIM;
    #pragma unroll
    for (int r = 0; r < 4; r++) {
        const int m = w * 16 + quad * 4 + r;
        if (m < NTOK) {
            Ob[(size_t)m * CDIM + l15]      = __float2bfloat16(o0[r]);
            Ob[(size_t)m * CDIM + 16 + l15] = __float2bfloat16(o1[r]);
        }
    }
}

extern "C" void kernel_launch(void* const* d_in, const int* in_sizes, int n_in,
                              void* d_out, int out_size, void* d_ws, size_t ws_size,
                              hipStream_t stream) {
    const float* x      = (const float*)d_in[0];
    const float* mask   = (const float*)d_in[1];
    const float* fg     = (const float*)d_in[2];
    const float* bg     = (const float*)d_in[3];
    const float* qkv_w  = (const float*)d_in[4];
    const float* qkv_b  = (const float*)d_in[5];
    const float* proj_w = (const float*)d_in[6];
    const float* proj_b = (const float*)d_in[7];
    const float* table  = (const float*)d_in[8];
    float* out = (float*)d_out;

    // workspace layout:
    //   [0,          51,380,224)  Obf (bf16 attn output)
    //   [205,520,896,213,909,504) wmp  (8,388,608)
    //   [213,909,504,233,578,496) Fgp (19,668,992)
    //   [233,578,496,253,247,488) Bgp (19,668,992)
    //   [256,901,120,257,294,336) qwb
    //   [257,294,336,257,425,408) pwb
    char* ws = (char*)d_ws;
    __hip_bfloat16* Obf = (__hip_bfloat16*)(ws);
    float* wmp = (float*)(ws + 205520896);
    float* Fgp = (float*)(ws + 213909504);
    float* Bgp = (float*)(ws + 233578496);
    __hip_bfloat16* qwb = (__hip_bfloat16*)(ws + 256901120);
    __hip_bfloat16* pwb = (__hip_bfloat16*)(ws + 257294336);

    dim3 blk(256);
    pre_masks<<<dim3(17924), blk, 0, stream>>>(
        qkv_w, proj_w, mask, table, fg, bg, qwb, pwb, wmp, Fgp, Bgp);
    fused_attn<<<dim3(B_TOT * NHEAD), blk, 0, stream>>>(
        x, qwb, qkv_b, wmp, Fgp, Bgp, Obf);
    gemm_mfma<CDIM, false><<<dim3(CDIM / 128, MROWS / 128), blk, 0, stream>>>(
        Obf, pwb, proj_b, out);
}

// Round 11
// 410.067 us; speedup vs baseline: 1.2080x; 1.2080x over previous
//
#include <hip/hip_runtime.h>
#include <hip/hip_bf16.h>
#include <hip/hip_fp16.h>
#include <math.h>

// WindowAttention on MI355X — round 14: vectorized GEMM epilogue + fp16 masks.
// Round-13 fusion regressed (282µs: scattered W loads, 8x x-staging, wave
// imbalance) — reverted to the round-9 separate-kernel pipeline.
// Evidence: qkv GEMM = 87µs for a 150MB write-dominated job (FETCH 27MB,
// write BW 1.7 TB/s vs 6.8 memset): epilogue issues 64 scalar 2B stores per
// thread. Deltas on the proven base:
//  1. operand-swapped MFMA (proven bit-identical in round 6's passing run):
//     thread holds 4 consecutive n => 16x uint2/float4 stores instead of 64
//     scalar; float4 bias loads. Staging loop byte-identical to the 87µs one.
//  2. Fgp/Bgp stored fp16 (0.05% rel err on a multiplicative factor; absmax
//     headroom 5x): halves pre-write + attn mask-fetch traffic.

#define B_TOT   2048
#define NTOK    49
#define CDIM    256
#define NHEAD   8
#define HDIM    32
#define MROWS   (B_TOT * NTOK)   // 100352
#define QKV_N   (3 * CDIM)       // 768

#define LOG2E 1.4426950408889634f

#if __has_builtin(__builtin_amdgcn_exp2f)
#define EXP2(x) __builtin_amdgcn_exp2f(x)
#else
#define EXP2(x) __expf((x) * 0.6931471805599453f)
#endif

typedef __attribute__((ext_vector_type(8))) short short8;   // 8 bf16 (4 VGPRs)
typedef __attribute__((ext_vector_type(4))) float floatx4;  // MFMA acc

typedef unsigned int u32_g __attribute__((address_space(1)));
typedef unsigned int u32_l __attribute__((address_space(3)));

__device__ __forceinline__ void gld_lds16(const void* g, void* l) {
    __builtin_amdgcn_global_load_lds((const u32_g*)g, (u32_l*)l, 16, 0, 0);
}

__device__ __forceinline__ void cast8(const float* __restrict__ in,
                                      __hip_bfloat16* __restrict__ out, int i) {
    const float4* p = (const float4*)in + (size_t)i * 2;
    float4 a = p[0], b = p[1];
    __hip_bfloat16 r[8];
    r[0] = __float2bfloat16(a.x); r[1] = __float2bfloat16(a.y);
    r[2] = __float2bfloat16(a.z); r[3] = __float2bfloat16(a.w);
    r[4] = __float2bfloat16(b.x); r[5] = __float2bfloat16(b.y);
    r[6] = __float2bfloat16(b.z); r[7] = __float2bfloat16(b.w);
    *(uint4*)(out + (size_t)i * 8) = *(const uint4*)r;
}

// exp -> fp16, 4 elems/thread (8B store).
__device__ __forceinline__ void exp4h(const float* __restrict__ in,
                                      __half* __restrict__ out, int i) {
    float4 a = ((const float4*)in)[i];
    __half r[4];
    r[0] = __float2half(EXP2(a.x * LOG2E));
    r[1] = __float2half(EXP2(a.y * LOG2E));
    r[2] = __float2half(EXP2(a.z * LOG2E));
    r[3] = __float2half(EXP2(a.w * LOG2E));
    *(uint2*)(out + (size_t)i * 4) = *(const uint2*)r;
}

// ---------------------------------------------------------------------------
// fused pre-kernel: block-range dispatch over 6 independent elementwise jobs.
//  [    0,12544): cast x      fp32->bf16, 8/thread
//  [12544,12640): cast qkv_w
//  [12640,12672): cast proj_w
//  [12672,20864): wmp[win][h][r64][c64] = (wmask + relpos)*log2e, pad -1e30
//  [20864,25666): Fgp = exp(fg) fp16
//  [25666,30468): Bgp = exp(bg) fp16
// ---------------------------------------------------------------------------
__global__ __launch_bounds__(256) void pre_kernel(
    const float* __restrict__ x,       // (100352, 256)
    const float* __restrict__ qkv_w,   // (768, 256)
    const float* __restrict__ proj_w,  // (256, 256)
    const float* __restrict__ wmask,   // (64, 49, 49)
    const float* __restrict__ table,   // (169, 8)
    const float* __restrict__ fg,      // (2048, 49, 49)
    const float* __restrict__ bg,      // (2048, 49, 49)
    __hip_bfloat16* __restrict__ xb,
    __hip_bfloat16* __restrict__ qwb,
    __hip_bfloat16* __restrict__ pwb,
    float* __restrict__ wmp,           // (64, 8, 64, 64)
    __half* __restrict__ Fgp,
    __half* __restrict__ Bgp)
{
    const int bid = blockIdx.x;
    const int t = threadIdx.x;
    if (bid < 12544) {
        cast8(x, xb, bid * 256 + t);
    } else if (bid < 12640) {
        cast8(qkv_w, qwb, (bid - 12544) * 256 + t);
    } else if (bid < 12672) {
        cast8(proj_w, pwb, (bid - 12640) * 256 + t);
    } else if (bid < 20864) {
        const int idx = (bid - 12672) * 256 + t;   // < 2^21
        const int col = idx & 63, row = (idx >> 6) & 63;
        const int h = (idx >> 12) & 7, win = idx >> 15;
        float v = -1e30f;
        if (row < 49 && col < 49) {
            const int qi = row / 7, qj = row % 7;
            const int ki = col / 7, kj = col % 7;
            const int ti = (qi - ki + 6) * 13 + (qj - kj + 6);
            v = (wmask[win * 2401 + row * 49 + col] + table[ti * 8 + h]) * LOG2E;
        }
        wmp[idx] = v;
    } else if (bid < 25666) {
        exp4h(fg, Fgp, (bid - 20864) * 256 + t);
    } else {
        exp4h(bg, Bgp, (bid - 25666) * 256 + t);
    }
}

// ---------------------------------------------------------------------------
// MFMA GEMM: Y(M,NDIM) = A(M,256) @ W(NDIM,256)^T + bias.
// Staging loop identical to the proven round-9 kernel (gld_lds, 128x128 tile,
// 4 K-steps, 2 barriers/step, XCD swizzle). Delta: operand-swapped MFMA
// (mfma(bf,af)) so each thread holds 4 CONSECUTIVE n per fragment =>
// vectorized epilogue: 16x uint2 (bf16) / 16x float4 (fp32) stores.
// Swap correctness + absmax proven in round 6's passing run.
// ---------------------------------------------------------------------------
template<int NDIM, bool OUT_BF16>
__global__ __launch_bounds__(256) void gemm_mfma(
    const __hip_bfloat16* __restrict__ A,
    const __hip_bfloat16* __restrict__ W,
    const float* __restrict__ bias,
    void* __restrict__ Yv)
{
    const int K = 256;
    __shared__ short As[128 * 64];
    __shared__ short Bs[128 * 64];
    const int t = threadIdx.x;
    const int lane = t & 63, w = t >> 6;
    const int wr = w >> 1, wc = w & 1;
    const int q = lane >> 4, l15 = lane & 15;

    constexpr int NBX = NDIM / 128;          // grid x
    constexpr int NWG = NBX * (MROWS / 128); // total blocks, % 8 == 0
    int bid = blockIdx.y * NBX + blockIdx.x; // HW dispatch linearization
    bid = (bid & 7) * (NWG >> 3) + (bid >> 3);  // chunk-per-XCD, bijective
    const int m0 = (bid / NBX) * 128, n0 = (bid % NBX) * 128;

    const int srow = t >> 3, skb = t & 7;
    const int gkb = skb ^ (srow & 7);
    const __hip_bfloat16* Ag = A + (size_t)(m0 + srow) * K + gkb * 8;
    const __hip_bfloat16* Wg = W + (size_t)(n0 + srow) * K + gkb * 8;

    floatx4 acc[4][4] = {};
    const int swz = l15 & 7;

    for (int k0 = 0; k0 < K; k0 += 64) {
        __syncthreads();
        #pragma unroll
        for (int i = 0; i < 4; i++) {
            gld_lds16(Ag + (size_t)(i * 32) * K + k0, &As[i * 2048 + w * 512]);
            gld_lds16(Wg + (size_t)(i * 32) * K + k0, &Bs[i * 2048 + w * 512]);
        }
        __syncthreads();
        #pragma unroll
        for (int kk = 0; kk < 2; kk++) {
            const int kbs = ((kk << 2) + q) ^ swz;
            short8 af[4], bf[4];
            #pragma unroll
            for (int i = 0; i < 4; i++) {
                af[i] = *(const short8*)&As[(wr * 64 + i * 16 + l15) * 64 + kbs * 8];
                bf[i] = *(const short8*)&Bs[(wc * 64 + i * 16 + l15) * 64 + kbs * 8];
            }
            #pragma unroll
            for (int i = 0; i < 4; i++)
                #pragma unroll
                for (int j = 0; j < 4; j++)
                    acc[i][j] = __builtin_amdgcn_mfma_f32_16x16x32_bf16(
                        bf[j], af[i], acc[i][j], 0, 0, 0);  // swapped operands
        }
    }

    // epilogue: m = m0+wr*64+i*16+l15 (per-thread row), n = n0+wc*64+j*16+q*4
    // (+reg r) => 4 consecutive n per (i,j): vectorized stores.
    float4 bv[4];
    #pragma unroll
    for (int j = 0; j < 4; j++)
        bv[j] = *(const float4*)&bias[n0 + wc * 64 + j * 16 + q * 4];
    #pragma unroll
    for (int i = 0; i < 4; i++) {
        const size_t mrow = (size_t)(m0 + wr * 64 + i * 16 + l15) * NDIM;
        #pragma unroll
        for (int j = 0; j < 4; j++) {
            const int n = n0 + wc * 64 + j * 16 + q * 4;
            const float v0 = acc[i][j][0] + bv[j].x;
            const float v1 = acc[i][j][1] + bv[j].y;
            const float v2 = acc[i][j][2] + bv[j].z;
            const float v3 = acc[i][j][3] + bv[j].w;
            if (OUT_BF16) {
                __hip_bfloat16 o[4] = {__float2bfloat16(v0), __float2bfloat16(v1),
                                       __float2bfloat16(v2), __float2bfloat16(v3)};
                *(uint2*)((__hip_bfloat16*)Yv + mrow + n) = *(const uint2*)o;
            } else {
                float4 o = {v0, v1, v2, v3};
                *(float4*)((float*)Yv + mrow + n) = o;
            }
        }
    }
}

// ---------------------------------------------------------------------------
// MFMA attention, one block (4 waves) per (b,h). 2 barriers. Math identical
// to rounds 8-12 (passed, absmax 0.00195) except Fgp/Bgp are fp16.
// LDS (24.1 KB): sQ 64x40 bf16 | sK 64x40 | sVt 32x72 | sP 64x72.
// Garbage policy: sK pad rows zeroed => pad-col acc == 0 => e0 = 0 exactly.
// Garbage Q rows -> NaN in sP rows >= 49 only -> discarded at store.
// ---------------------------------------------------------------------------
__global__ __launch_bounds__(256, 6) void attn_kernel(
    const __hip_bfloat16* __restrict__ Y,   // (B*49, 768) bf16
    const float* __restrict__ wmp,          // (64, 8, 64, 64) prepped
    const __half* __restrict__ Fgp,         // (B, 49, 49) = exp(fg) fp16
    const __half* __restrict__ Bgp,         // (B, 49, 49) = exp(bg) fp16
    __hip_bfloat16* __restrict__ O)         // (B*49, 256) bf16 -> ws
{
    __shared__ __hip_bfloat16 sQ[64 * 40];
    __shared__ __hip_bfloat16 sK[64 * 40];
    __shared__ __hip_bfloat16 sVt[32 * 72];
    __shared__ __hip_bfloat16 sP[64 * 72];

    const int blk = blockIdx.x;
    const int b = (blk >> 6) * 8 + (blk & 7);
    const int h = (blk >> 3) & 7;
    const int t = threadIdx.x;
    const int w = t >> 6, lane = t & 63;
    const int quad = lane >> 4, l15 = lane & 15;
    const float SC = 0.17677669529663687f * LOG2E;  // hd^-0.5 * log2e

    // ---- phase A ----
    const float* wmb = wmp + (((size_t)(b & 63) * 8 + h) << 12);
    const __half* fgb = Fgp + (size_t)b * (NTOK * NTOK);
    const __half* bgb = Bgp + (size_t)b * (NTOK * NTOK);
    float mwm[16], mfg[16], mbg[16];
    #pragma unroll
    for (int r = 0; r < 4; r++) {
        const int row = w * 16 + quad * 4 + r;
        const int rc49 = min(row, 48) * 49;
        const float* pw = wmb + row * 64 + l15;
        const __half* pf = fgb + rc49 + l15;
        const __half* pb = bgb + rc49 + l15;
        mwm[r * 4 + 0] = pw[0];  mwm[r * 4 + 1] = pw[16];
        mwm[r * 4 + 2] = pw[32]; mwm[r * 4 + 3] = pw[48];
        mfg[r * 4 + 0] = __half2float(pf[0]);
        mfg[r * 4 + 1] = __half2float(pf[16]);
        mfg[r * 4 + 2] = __half2float(pf[32]);
        mfg[r * 4 + 3] = __half2float(fgb[rc49 + 48]);
        mbg[r * 4 + 0] = __half2float(pb[0]);
        mbg[r * 4 + 1] = __half2float(pb[16]);
        mbg[r * 4 + 2] = __half2float(pb[32]);
        mbg[r * 4 + 3] = __half2float(bgb[rc49 + 48]);
    }
    // stage Q, K row-major (stride 40); V transposed (stride 72)
    const __hip_bfloat16* Yb = Y + (size_t)b * NTOK * QKV_N + h * HDIM;
    if (t < 196) {
        const int n = t >> 2, c = t & 3;  // row, 8-elem chunk
        uint4 qv = *(const uint4*)(Yb + (size_t)n * QKV_N + c * 8);
        uint4 kv = *(const uint4*)(Yb + (size_t)n * QKV_N + 256 + c * 8);
        uint4 vv = *(const uint4*)(Yb + (size_t)n * QKV_N + 512 + c * 8);
        *(uint4*)(sQ + n * 40 + c * 8) = qv;
        *(uint4*)(sK + n * 40 + c * 8) = kv;
        const __hip_bfloat16* vp = (const __hip_bfloat16*)&vv;
        #pragma unroll
        for (int j = 0; j < 8; j++)
            sVt[(c * 8 + j) * 72 + n] = vp[j];
    }
    // zero sK rows 49..63 (flat dwords [980,1280); disjoint from staging).
    {
        unsigned int* pK = (unsigned int*)sK;
        #pragma unroll
        for (int i = 980 + t; i < 1280; i += 256) pK[i] = 0u;
    }
    // zero Vt k-pad: cols 49..64 of 32 rows.
    {
        const __hip_bfloat16 z = __float2bfloat16(0.f);
        #pragma unroll
        for (int it = 0; it < 2; it++) {
            const int idx = t + it * 256;  // 0..511
            const int d = idx >> 4, c = 49 + (idx & 15);
            sVt[d * 72 + c] = z;
        }
    }
    __syncthreads();

    // ---- phase B: S = Q K^T in registers ----
    floatx4 acc[4];
    {
        short8 af = *(const short8*)(sQ + (w * 16 + l15) * 40 + quad * 8);
        #pragma unroll
        for (int nt = 0; nt < 4; nt++) {
            short8 bf = *(const short8*)(sK + (nt * 16 + l15) * 40 + quad * 8);
            floatx4 z = {};
            acc[nt] = __builtin_amdgcn_mfma_f32_16x16x32_bf16(af, bf, z, 0, 0, 0);
        }
    }

    // unnormalized exponentials (exp2 domain; wmp pre-scaled by log2e).
    float e0[16];
    #pragma unroll
    for (int r = 0; r < 4; r++)
        #pragma unroll
        for (int nt = 0; nt < 4; nt++)
            e0[r * 4 + nt] = EXP2(fmaf(acc[nt][r], SC, mwm[r * 4 + nt]));
    #pragma unroll
    for (int i = 0; i < 16; i++) mfg[i] *= e0[i];   // ef
    #pragma unroll
    for (int i = 0; i < 16; i++) mbg[i] *= e0[i];   // eb

    // 3 row-sum reductions, quad-local 4-step shuffles.
    float s0[4], sf[4], sb[4];
    #pragma unroll
    for (int r = 0; r < 4; r++) {
        s0[r] = (e0[r * 4] + e0[r * 4 + 1]) + (e0[r * 4 + 2] + e0[r * 4 + 3]);
        sf[r] = (mfg[r * 4] + mfg[r * 4 + 1]) + (mfg[r * 4 + 2] + mfg[r * 4 + 3]);
        sb[r] = (mbg[r * 4] + mbg[r * 4 + 1]) + (mbg[r * 4 + 2] + mbg[r * 4 + 3]);
    }
    #pragma unroll
    for (int st = 1; st < 16; st <<= 1)
        #pragma unroll
        for (int r = 0; r < 4; r++) {
            s0[r] += __shfl_xor(s0[r], st);
            sf[r] += __shfl_xor(sf[r], st);
            sb[r] += __shfl_xor(sb[r], st);
        }

    float pc[16];
    #pragma unroll
    for (int r = 0; r < 4; r++) {
        const float r0 = __builtin_amdgcn_rcpf(s0[r]);
        const float rf = __builtin_amdgcn_rcpf(sf[r]);
        const float rb = -__builtin_amdgcn_rcpf(sb[r]);
        #pragma unroll
        for (int nt = 0; nt < 4; nt++) {
            const int i = r * 4 + nt;
            pc[i] = fmaf(mbg[i], rb, fmaf(mfg[i], rf, e0[i] * r0));
        }
    }

    // P -> LDS (bf16, row-major stride 72 = A-operand layout for PV).
    #pragma unroll
    for (int r = 0; r < 4; r++) {
        const int row = w * 16 + quad * 4 + r;
        #pragma unroll
        for (int nt = 0; nt < 4; nt++)
            sP[row * 72 + nt * 16 + l15] = __float2bfloat16(pc[r * 4 + nt]);
    }
    __syncthreads();

    // ---- phase C: O = P @ V ----
    floatx4 o0 = {}, o1 = {};
    {
        short8 a0  = *(const short8*)(sP + (w * 16 + l15) * 72 + quad * 8);
        short8 a1  = *(const short8*)(sP + (w * 16 + l15) * 72 + 32 + quad * 8);
        short8 b00 = *(const short8*)(sVt + l15 * 72 + quad * 8);
        short8 b01 = *(const short8*)(sVt + l15 * 72 + 32 + quad * 8);
        short8 b10 = *(const short8*)(sVt + (16 + l15) * 72 + quad * 8);
        short8 b11 = *(const short8*)(sVt + (16 + l15) * 72 + 32 + quad * 8);
        o0 = __builtin_amdgcn_mfma_f32_16x16x32_bf16(a0, b00, o0, 0, 0, 0);
        o0 = __builtin_amdgcn_mfma_f32_16x16x32_bf16(a1, b01, o0, 0, 0, 0);
        o1 = __builtin_amdgcn_mfma_f32_16x16x32_bf16(a0, b10, o1, 0, 0, 0);
        o1 = __builtin_amdgcn_mfma_f32_16x16x32_bf16(a1, b11, o1, 0, 0, 0);
    }
    __hip_bfloat16* Ob = O + (size_t)b * NTOK * CDIM + h * HDIM;
    #pragma unroll
    for (int r = 0; r < 4; r++) {
        const int m = w * 16 + quad * 4 + r;
        if (m < NTOK) {
            Ob[(size_t)m * CDIM + l15]      = __float2bfloat16(o0[r]);
            Ob[(size_t)m * CDIM + 16 + l15] = __float2bfloat16(o1[r]);
        }
    }
}

extern "C" void kernel_launch(void* const* d_in, const int* in_sizes, int n_in,
                              void* d_out, int out_size, void* d_ws, size_t ws_size,
                              hipStream_t stream) {
    const float* x      = (const float*)d_in[0];
    const float* mask   = (const float*)d_in[1];
    const float* fg     = (const float*)d_in[2];
    const float* bg     = (const float*)d_in[3];
    const float* qkv_w  = (const float*)d_in[4];
    const float* qkv_b  = (const float*)d_in[5];
    const float* proj_w = (const float*)d_in[6];
    const float* proj_b = (const float*)d_in[7];
    const float* table  = (const float*)d_in[8];
    float* out = (float*)d_out;

    // workspace layout:
    //   [0,          51,380,224)  xb (bf16 x)  -> reused as Obf by attn
    //   [51,380,224, 205,520,896) Ybf
    //   [205,520,896,213,909,504) wmp (8,388,608 fp32)
    //   [213,909,504,223,744,000) Fgp (9,834,496 fp16)
    //   [223,744,000,233,578,496) Bgp (9,834,496 fp16)
    //   [256,901,120,257,294,336) qwb
    //   [257,294,336,257,425,408) pwb
    char* ws = (char*)d_ws;
    __hip_bfloat16* xb  = (__hip_bfloat16*)(ws);
    __hip_bfloat16* Ybf = (__hip_bfloat16*)(ws + 51380224);
    float* wmp  = (float*)(ws + 205520896);
    __half* Fgp = (__half*)(ws + 213909504);
    __half* Bgp = (__half*)(ws + 223744000);
    __hip_bfloat16* qwb = (__hip_bfloat16*)(ws + 256901120);
    __hip_bfloat16* pwb = (__hip_bfloat16*)(ws + 257294336);
    __hip_bfloat16* Obf = xb;   // xb dead after gemm_qkv; attn writes here

    dim3 blk(256);
    pre_kernel<<<dim3(30468), blk, 0, stream>>>(
        x, qkv_w, proj_w, mask, table, fg, bg, xb, qwb, pwb, wmp, Fgp, Bgp);
    gemm_mfma<QKV_N, true><<<dim3(QKV_N / 128, MROWS / 128), blk, 0, stream>>>(xb, qwb, qkv_b, Ybf);
    attn_kernel<<<dim3(B_TOT * NHEAD), blk, 0, stream>>>(Ybf, wmp, Fgp, Bgp, Obf);
    gemm_mfma<CDIM, false><<<dim3(CDIM / 128, MROWS / 128), blk, 0, stream>>>(Obf, pwb, proj_b, out);
}